// Round 6
// baseline (100.859 us; speedup 1.0000x reference)
//
#include <hip/hip_runtime.h>
#include <hip/hip_fp16.h>

// StableTTLayer TT forward, B=131072. Round 6: block-local bucketing.
// R5 was L2-vector-path bound (1.10 GB gathers @ 26.9 TB/s ceiling). R6 keeps
// the R5 tables (T01/PK/TL, validated) but each block (512 samples) counting-
// sorts its samples by column per middle stage in LDS; waves then process 8
// same-column samples -> matrix dwordx4 reads merge to ~2 lines/instr
// (~4x less L2 matrix traffic). v between stages lives in LDS (80B stride,
// 16B-aligned, bank-spread). Still exactly 2 dispatches (overhead: ~5us/extra).
// Scales baked: 256 * 16^4 * 256 = 2^32, undone exactly at the end.
// Norm stabilization cancels exactly -> skipped (validated R1-R5).

#define B_TOTAL 131072
#define NDIM 64
#define RANK 32
#define S_BLK 512
#define THREADS 1024
#define VSTRIDE 20   // u32 stride per sample (80 B): 16B-aligned, bank-spread

typedef _Float16 half2_t __attribute__((ext_vector_type(2)));
union H2 { unsigned int u; half2_t h; __half2 hh; };

#if defined(__has_builtin)
#if __has_builtin(__builtin_amdgcn_fdot2)
#define HAVE_FDOT2 1
#endif
#endif

// ---------------- K1: build all tables (unchanged from R5, validated) -------
__global__ __launch_bounds__(256) void build_tables(
    const float* __restrict__ core0, const float* __restrict__ mid,
    const float* __restrict__ lastc,
    __half2* __restrict__ PK, __half* __restrict__ T01, float* __restrict__ TL)
{
    const int id = blockIdx.x * 256 + threadIdx.x;
    if (id < 131072) {
        // PK[((tt*64+c)*16+r2)*32+s] = half2(16*m[2r2], 16*m[2r2+1]), m=mid[1+tt]
        const int s = id & 31, r2 = (id >> 5) & 15, c = (id >> 9) & 63, tt = id >> 15;
        const int t = 1 + tt;
        const float a = mid[((t * 32 + 2 * r2 + 0) * 64 + c) * 32 + s];
        const float b = mid[((t * 32 + 2 * r2 + 1) * 64 + c) * 32 + s];
        H2 p; p.hh = __float22half2_rn(make_float2(a * 16.f, b * 16.f));
        PK[id] = p.hh;
    } else if (id < 262144) {
        const int i2 = id - 131072;
        const int s = i2 & 31, c1 = (i2 >> 5) & 63, c0 = i2 >> 11;
        float acc = 0.f;
        #pragma unroll
        for (int r = 0; r < 32; ++r)
            acc = fmaf(core0[c0 * 32 + r], mid[(r * 64 + c1) * 32 + s], acc);
        T01[(c0 * 64 + c1) * 32 + s] = __float2half(acc * 256.0f);
    } else {
        const int i3 = id - 262144;
        const int c7 = i3 & 63, c6 = (i3 >> 6) & 63, r = i3 >> 12;
        const float* m5 = mid + 5 * 65536;
        float acc = 0.f;
        #pragma unroll
        for (int s = 0; s < 32; ++s)
            acc = fmaf(m5[(r * 64 + c6) * 32 + s], lastc[s * 64 + c7], acc);
        TL[(c6 * 64 + c7) * 32 + r] = acc * 256.0f;
    }
}

// ---------------- K2: main — block-bucketed ---------------------------------
__global__ __launch_bounds__(1024) void tt_main_bucket(
    const int* __restrict__ idx, const __half* __restrict__ T01,
    const __half2* __restrict__ PK, const float* __restrict__ TL,
    float* __restrict__ out)
{
    __shared__ unsigned int   vbuf[S_BLK * VSTRIDE];   // 40 KB: v per sample (16 u32 used)
    __shared__ unsigned short ord[4][S_BLK];           // 4 KB: sorted (sample | key<<9)
    __shared__ unsigned char  cols[S_BLK][8];          // 4 KB: clamped indices
    __shared__ unsigned int   hist[64], basev[64];

    const int tid   = threadIdx.x;
    const int wave  = tid >> 6;          // 0..15
    const int glane = tid & 7;           // lane within 8-lane group
    const int gid   = tid >> 3;          // 0..127: group id in block
    const int gl    = gid & 7;           // group id within wave
    const int b0    = blockIdx.x * S_BLK;

    // Phase 0: idx -> cols (coalesced; 4096 ints per block)
    #pragma unroll
    for (int k = 0; k < 4096; k += THREADS) {
        const int lin = k + tid;
        int v = idx[b0 * 8 + lin];
        v = min(max(v, 0), NDIM - 1);
        cols[lin >> 3][lin & 7] = (unsigned char)v;
    }
    __syncthreads();

    // Phase 1: four local counting sorts (keys c2..c5)
    for (int tt = 0; tt < 4; ++tt) {
        if (tid < 64) hist[tid] = 0;
        __syncthreads();
        unsigned int key = 0, arr = 0;
        if (tid < S_BLK) {
            key = cols[tid][2 + tt];
            arr = atomicAdd(&hist[key], 1u);
        }
        __syncthreads();
        if (tid < 64) {                        // wave 0: exclusive scan of 64 bins
            const unsigned int v = hist[tid];
            unsigned int inc = v;
            #pragma unroll
            for (int d = 1; d < 64; d <<= 1) {
                const unsigned int n = __shfl_up(inc, d);
                if (tid >= d) inc += n;
            }
            basev[tid] = inc - v;
        }
        __syncthreads();
        if (tid < S_BLK)
            ord[tt][basev[key] + arr] = (unsigned short)(tid | (key << 9));
        __syncthreads();
    }

    // Phase 2: T01 init -> vbuf (x256 true value, fp16 pairs)
    #pragma unroll
    for (int p = 0; p < S_BLK / 128; ++p) {
        const int s = p * 128 + gid;
        const int c0 = cols[s][0], c1 = cols[s][1];
        const uint2 q = *reinterpret_cast<const uint2*>(
            T01 + (c0 * 64 + c1) * 32 + 4 * glane);
        vbuf[s * VSTRIDE + glane * 2]     = q.x;
        vbuf[s * VSTRIDE + glane * 2 + 1] = q.y;
    }
    __syncthreads();

    // Phase 3: 4 middle stages, sorted order (waves see ~1-2 distinct columns)
    #pragma unroll 1
    for (int tt = 0; tt < 4; ++tt) {
        #pragma unroll 1
        for (int p = 0; p < 4; ++p) {
            const int pos = (wave * 4 + p) * 8 + gl;        // 8 consecutive per wave
            const unsigned int e = ord[tt][pos];
            const int s = e & 511;
            const int c = e >> 9;
            const __half2* M = PK + ((tt * 64 + c) * 16) * 32 + 4 * glane;

            float a0 = 0.f, a1 = 0.f, a2 = 0.f, a3 = 0.f;
            #pragma unroll
            for (int r2 = 0; r2 < 16; ++r2) {
                H2 vp; vp.u = vbuf[s * VSTRIDE + r2];       // group-broadcast read
                const uint4 mr = *reinterpret_cast<const uint4*>(M + r2 * 32);
                H2 m0, m1, m2, m3;
                m0.u = mr.x; m1.u = mr.y; m2.u = mr.z; m3.u = mr.w;
#ifdef HAVE_FDOT2
                a0 = __builtin_amdgcn_fdot2(vp.h, m0.h, a0, false);
                a1 = __builtin_amdgcn_fdot2(vp.h, m1.h, a1, false);
                a2 = __builtin_amdgcn_fdot2(vp.h, m2.h, a2, false);
                a3 = __builtin_amdgcn_fdot2(vp.h, m3.h, a3, false);
#else
                const float vl = __low2float(vp.hh), vh = __high2float(vp.hh);
                a0 = fmaf(vl, __low2float(m0.hh), fmaf(vh, __high2float(m0.hh), a0));
                a1 = fmaf(vl, __low2float(m1.hh), fmaf(vh, __high2float(m1.hh), a1));
                a2 = fmaf(vl, __low2float(m2.hh), fmaf(vh, __high2float(m2.hh), a2));
                a3 = fmaf(vl, __low2float(m3.hh), fmaf(vh, __high2float(m3.hh), a3));
#endif
            }
            // write back this sample's new v (slot is sample-private this stage)
            H2 n01, n23;
            n01.hh = __float22half2_rn(make_float2(a0, a1));
            n23.hh = __float22half2_rn(make_float2(a2, a3));
            vbuf[s * VSTRIDE + glane * 2]     = n01.u;
            vbuf[s * VSTRIDE + glane * 2 + 1] = n23.u;
        }
        __syncthreads();
    }

    // Phase 4: TL final contraction, 8-lane reduce, undo 2^32
    #pragma unroll
    for (int p = 0; p < S_BLK / 128; ++p) {
        const int s = p * 128 + gid;
        const int c6 = cols[s][6], c7 = cols[s][7];
        H2 v01, v23;
        v01.u = vbuf[s * VSTRIDE + glane * 2];
        v23.u = vbuf[s * VSTRIDE + glane * 2 + 1];
        const float4 L = *reinterpret_cast<const float4*>(
            TL + (c6 * 64 + c7) * 32 + 4 * glane);
        float o = 0.f;
        o = fmaf(__low2float(v01.hh),  L.x, o);
        o = fmaf(__high2float(v01.hh), L.y, o);
        o = fmaf(__low2float(v23.hh),  L.z, o);
        o = fmaf(__high2float(v23.hh), L.w, o);
        o += __shfl_xor(o, 1);
        o += __shfl_xor(o, 2);
        o += __shfl_xor(o, 4);
        if (glane == 0) out[b0 + s] = o * 2.3283064365386963e-10f;   // 2^-32
    }
}

// ---------------- host -------------------------------------------------------
// ws layout: PK 524288 B | TL 524288 B | T01 262144 B   (total 1310720 B)
#define PK_OFF  0u
#define TL_OFF  524288u
#define T01_OFF 1048576u

extern "C" void kernel_launch(void* const* d_in, const int* in_sizes, int n_in,
                              void* d_out, int out_size, void* d_ws, size_t ws_size,
                              hipStream_t stream) {
    const int*   idx   = (const int*)d_in[0];    // (B, 8) int32
    const float* core0 = (const float*)d_in[1];  // (1, 64, 32)
    const float* mid   = (const float*)d_in[2];  // (6, 32, 64, 32)
    const float* lastc = (const float*)d_in[3];  // (32, 64, 1)
    float* out = (float*)d_out;

    __half2* PK  = (__half2*)((char*)d_ws + PK_OFF);
    float*   TL  = (float*)((char*)d_ws + TL_OFF);
    __half*  T01 = (__half*)((char*)d_ws + T01_OFF);

    hipLaunchKernelGGL(build_tables, dim3(393216 / 256), dim3(256), 0, stream,
                       core0, mid, lastc, PK, T01, TL);
    hipLaunchKernelGGL(tt_main_bucket, dim3(B_TOTAL / S_BLK), dim3(THREADS), 0, stream,
                       idx, T01, PK, TL, out);
}

// Round 7
// 91.097 us; speedup vs baseline: 1.1072x; 1.1072x over previous
//
#include <hip/hip_runtime.h>
#include <hip/hip_fp16.h>

// StableTTLayer TT forward, B=131072. Round 7: MFMA-batched bucketing.
// R6 falsified "L2 unique-byte-rate bound": dedup'ing lines changed nothing.
// True invariant: bytes delivered into VGPRs (~45-50 B/cyc/CU). R7 makes the
// matrix enter registers once per 16 samples instead of once per sample:
// per column bucket (R6's validated sort), V_new(16x32) = V(16x32) @ M(32x32)
// via two mfma_f32_16x16x32_f16. B-operand (M) is pre-swizzled into MFMA
// fragment order at table-build time (PKB); A (V) comes from LDS vbuf via one
// ds_read_b128; D is scattered back to vbuf as fp16 (b16 writes).
// Tables/scales validated R5 (256 * 16^4 * 256 = 2^32, undone at end);
// A/B/D MFMA layouts validated R4; sort validated R6.

#define B_TOTAL 131072
#define NDIM 64
#define RANK 32
#define S_BLK 512
#define THREADS 512
#define VSTRIDE_H 40   // halves per sample slot in vbuf (80 B: 16B-aligned, bank-spread)

typedef _Float16 half8  __attribute__((ext_vector_type(8)));
typedef float    f32x4  __attribute__((ext_vector_type(4)));

// ---------------- K1: build tables ------------------------------------------
// ids [0,32768):        PKB  mid1..4 in MFMA-B fragment order, x16 baked
//                       PKB[((tt*64+c)*2+f)*64 + l][j] = 16*mid[1+tt][q*8+j][c][f*16+li]
//                       (l: q=l>>4, li=l&15)
// ids [32768,163840):   T01  (core0 . mid0), fp16, x256 baked
// ids [163840,294912):  TL   (mid5 . core_last), fp32, x256 baked
__global__ __launch_bounds__(256) void build_tables(
    const float* __restrict__ core0, const float* __restrict__ mid,
    const float* __restrict__ lastc,
    half8* __restrict__ PKB, __half* __restrict__ T01, float* __restrict__ TL)
{
    const int id = blockIdx.x * 256 + threadIdx.x;
    if (id < 32768) {
        const int l  = id & 63;
        const int f  = (id >> 6) & 1;
        const int c  = (id >> 7) & 63;
        const int tt = id >> 13;
        const int q = l >> 4, li = l & 15;
        const int n = f * 16 + li;
        const int t = 1 + tt;
        half8 h;
        #pragma unroll
        for (int j = 0; j < 8; ++j) {
            const int k = q * 8 + j;
            h[j] = (_Float16)(16.0f * mid[((t * 32 + k) * 64 + c) * 32 + n]);
        }
        PKB[id] = h;
    } else if (id < 163840) {
        const int i2 = id - 32768;
        const int s = i2 & 31, c1 = (i2 >> 5) & 63, c0 = i2 >> 11;
        float acc = 0.f;
        #pragma unroll
        for (int r = 0; r < 32; ++r)
            acc = fmaf(core0[c0 * 32 + r], mid[(r * 64 + c1) * 32 + s], acc);
        T01[(c0 * 64 + c1) * 32 + s] = __float2half(acc * 256.0f);
    } else {
        const int i3 = id - 163840;
        const int c7 = i3 & 63, c6 = (i3 >> 6) & 63, r = i3 >> 12;
        const float* m5 = mid + 5 * 65536;
        float acc = 0.f;
        #pragma unroll
        for (int s = 0; s < 32; ++s)
            acc = fmaf(m5[(r * 64 + c6) * 32 + s], lastc[s * 64 + c7], acc);
        TL[(c6 * 64 + c7) * 32 + r] = acc * 256.0f;
    }
}

// ---------------- K2: main --------------------------------------------------
__global__ __launch_bounds__(512) void tt_main_mfma(
    const int* __restrict__ idx, const __half* __restrict__ T01,
    const half8* __restrict__ PKB, const float* __restrict__ TL,
    float* __restrict__ out)
{
    __shared__ __align__(16) __half vbuf[S_BLK * VSTRIDE_H];  // 40 KB
    __shared__ unsigned short ord[4][S_BLK];                  // 4 KB
    __shared__ unsigned char  cols[S_BLK][8];                 // 4 KB
    __shared__ unsigned int   bases[4][65];                   // 1040 B
    __shared__ unsigned int   hist[64];

    const int tid  = threadIdx.x;
    const int lane = tid & 63;
    const int wv   = tid >> 6;          // 0..7
    const int li   = lane & 15;
    const int quad = lane >> 4;
    const int b0   = blockIdx.x * S_BLK;

    // Phase 0: indices -> cols (coalesced)
    #pragma unroll
    for (int k = 0; k < S_BLK * 8; k += THREADS) {
        const int lin = k + tid;
        int v = idx[b0 * 8 + lin];
        v = min(max(v, 0), NDIM - 1);
        cols[lin >> 3][lin & 7] = (unsigned char)v;
    }
    __syncthreads();

    // Phase 1: four counting sorts (keys c2..c5) -> ord + bases
    for (int tt = 0; tt < 4; ++tt) {
        if (tid < 64) hist[tid] = 0;
        __syncthreads();
        const unsigned int key = cols[tid][2 + tt];
        const unsigned int rank = atomicAdd(&hist[key], 1u);
        __syncthreads();
        if (tid < 64) {
            const unsigned int v = hist[tid];
            unsigned int inc = v;
            #pragma unroll
            for (int d = 1; d < 64; d <<= 1) {
                const unsigned int n = __shfl_up(inc, d);
                if (lane >= d) inc += n;
            }
            bases[tt][tid] = inc - v;
            if (tid == 63) bases[tt][64] = inc;   // 512
        }
        __syncthreads();
        ord[tt][bases[tt][key] + rank] = (unsigned short)tid;
        __syncthreads();
    }

    // Phase 2: init v from T01 (8-lane groups; x256 true value)
    {
        const int g = tid & 7, gid = tid >> 3;
        #pragma unroll
        for (int it = 0; it < S_BLK / 64; ++it) {
            const int s = it * 64 + gid;
            const int c0 = cols[s][0], c1 = cols[s][1];
            const uint2 q = *reinterpret_cast<const uint2*>(
                T01 + (c0 * 64 + c1) * 32 + 4 * g);
            unsigned int* vp = reinterpret_cast<unsigned int*>(vbuf) + s * (VSTRIDE_H / 2);
            vp[2 * g]     = q.x;
            vp[2 * g + 1] = q.y;
        }
    }
    __syncthreads();

    // Phase 3: 4 middle stages; wave wv owns columns [8wv, 8wv+8)
    for (int tt = 0; tt < 4; ++tt) {
        for (int c = wv * 8; c < wv * 8 + 8; ++c) {
            const int start = (int)bases[tt][c];
            const int end   = (int)bases[tt][c + 1];
            if (start == end) continue;
            // B fragments: M[c] once per column, coalesced dwordx4
            const half8 bf0 = PKB[((tt * 64 + c) * 2 + 0) * 64 + lane];
            const half8 bf1 = PKB[((tt * 64 + c) * 2 + 1) * 64 + lane];

            for (int p = start; p < end; p += 16) {
                const int pos = min(p + li, end - 1);
                const int sm  = (int)ord[tt][pos];
                // A: V rows, lane holds v[sm][quad*8 .. quad*8+7]
                const half8 A = *reinterpret_cast<const half8*>(
                    reinterpret_cast<const char*>(vbuf) + sm * 80 + quad * 16);
                f32x4 d0 = {0.f, 0.f, 0.f, 0.f}, d1 = {0.f, 0.f, 0.f, 0.f};
                d0 = __builtin_amdgcn_mfma_f32_16x16x32_f16(A, bf0, d0, 0, 0, 0);
                d1 = __builtin_amdgcn_mfma_f32_16x16x32_f16(A, bf1, d1, 0, 0, 0);
                // writeback: D row m = quad*4+r (sample), col = li (s index)
                #pragma unroll
                for (int r = 0; r < 4; ++r) {
                    const int mrow = quad * 4 + r;
                    const int s2 = __shfl(sm, mrow);   // lanes 0..15 hold batch order
                    if (p + mrow < end) {
                        vbuf[s2 * VSTRIDE_H + li]      = __float2half(d0[r]);
                        vbuf[s2 * VSTRIDE_H + 16 + li] = __float2half(d1[r]);
                    }
                }
            }
        }
        __syncthreads();
    }

    // Phase 4: final contraction vs TL (x256), 8-lane reduce, undo 2^32
    {
        const int g = tid & 7, gid = tid >> 3;
        #pragma unroll
        for (int it = 0; it < S_BLK / 64; ++it) {
            const int s = it * 64 + gid;
            const int c6 = cols[s][6], c7 = cols[s][7];
            const unsigned int* vp =
                reinterpret_cast<const unsigned int*>(vbuf) + s * (VSTRIDE_H / 2);
            const __half2 v01 = *reinterpret_cast<const __half2*>(&vp[2 * g]);
            const __half2 v23 = *reinterpret_cast<const __half2*>(&vp[2 * g + 1]);
            const float4 L = *reinterpret_cast<const float4*>(
                TL + (c6 * 64 + c7) * 32 + 4 * g);
            float o = 0.f;
            o = fmaf(__low2float(v01),  L.x, o);
            o = fmaf(__high2float(v01), L.y, o);
            o = fmaf(__low2float(v23),  L.z, o);
            o = fmaf(__high2float(v23), L.w, o);
            o += __shfl_xor(o, 1);
            o += __shfl_xor(o, 2);
            o += __shfl_xor(o, 4);
            if (g == 0) out[b0 + s] = o * 2.3283064365386963e-10f;   // 2^-32
        }
    }
}

// ---------------- host ------------------------------------------------------
// ws: PKB 524288 B | TL 524288 B | T01 262144 B  (1310720 B total, same as R5)
#define PKB_OFF 0u
#define TL_OFF  524288u
#define T01_OFF 1048576u

extern "C" void kernel_launch(void* const* d_in, const int* in_sizes, int n_in,
                              void* d_out, int out_size, void* d_ws, size_t ws_size,
                              hipStream_t stream) {
    const int*   idx   = (const int*)d_in[0];    // (B, 8) int32
    const float* core0 = (const float*)d_in[1];  // (1, 64, 32)
    const float* mid   = (const float*)d_in[2];  // (6, 32, 64, 32)
    const float* lastc = (const float*)d_in[3];  // (32, 64, 1)
    float* out = (float*)d_out;

    half8*  PKB = (half8*)((char*)d_ws + PKB_OFF);
    float*  TL  = (float*)((char*)d_ws + TL_OFF);
    __half* T01 = (__half*)((char*)d_ws + T01_OFF);

    hipLaunchKernelGGL(build_tables, dim3(294912 / 256), dim3(256), 0, stream,
                       core0, mid, lastc, PKB, T01, TL);
    hipLaunchKernelGGL(tt_main_mfma, dim3(B_TOTAL / S_BLK), dim3(THREADS), 0, stream,
                       idx, T01, PKB, TL, out);
}

// Round 8
// 84.210 us; speedup vs baseline: 1.1977x; 1.0818x over previous
//
#include <hip/hip_runtime.h>
#include <hip/hip_fp16.h>

// StableTTLayer TT forward, B=131072. Round 8.
// R7 post-mortem: global traffic solved (~35 MB total) but ~32us remained in
// serial overheads: shfl->8x ds_write_b16 writeback chain, 16 sort barriers
// at 1 block/CU, exposed per-column fragment loads, half-empty batches.
// R8: (1) TRANSPOSED MFMA: D = (M^T as A) x (V as B); PKB bytes identical,
//     V-read identical, but D writeback becomes 2x ds_write_b64 per batch
//     (no shfl, no guard - clamped dup lanes write identical bytes).
// (2) one fused counting-sort phase (4 barriers, ranks in registers).
// (3) 512 blocks x 256 threads (S_BLK=256, ~27KB LDS -> 2 blocks/CU overlap).
// (4) prefetch next column's A-fragments across the batch loop.
// Tables/scales validated R5/R7 (256 * 16^4 * 256 = 2^32, undone at end).

#define B_TOTAL 131072
#define NDIM 64
#define RANK 32
#define S_BLK 256
#define THREADS 256
#define VSTRIDE_H 40   // halves per sample slot (80 B: 16B-aligned, bank-spread)

typedef _Float16 half8 __attribute__((ext_vector_type(8)));
typedef _Float16 half4 __attribute__((ext_vector_type(4)));
typedef float    f32x4 __attribute__((ext_vector_type(4)));

// ---------------- K1: build tables (unchanged from R7, validated) -----------
// ids [0,32768):        PKB[((tt*64+c)*2+f)*64 + l][j]
//                         = 16*mid[1+tt][k=(l>>4)*8+j][c][f*16+(l&15)]
//                       (serves as A-fragment of M^T: A_f[m=li][k]=M[k][f*16+li])
// ids [32768,163840):   T01 (core0 . mid0), fp16, x256 baked
// ids [163840,294912):  TL  (mid5 . core_last), fp32, x256 baked
__global__ __launch_bounds__(256) void build_tables(
    const float* __restrict__ core0, const float* __restrict__ mid,
    const float* __restrict__ lastc,
    half8* __restrict__ PKB, __half* __restrict__ T01, float* __restrict__ TL)
{
    const int id = blockIdx.x * 256 + threadIdx.x;
    if (id < 32768) {
        const int l  = id & 63;
        const int f  = (id >> 6) & 1;
        const int c  = (id >> 7) & 63;
        const int tt = id >> 13;
        const int q = l >> 4, li = l & 15;
        const int n = f * 16 + li;
        const int t = 1 + tt;
        half8 h;
        #pragma unroll
        for (int j = 0; j < 8; ++j) {
            const int k = q * 8 + j;
            h[j] = (_Float16)(16.0f * mid[((t * 32 + k) * 64 + c) * 32 + n]);
        }
        PKB[id] = h;
    } else if (id < 163840) {
        const int i2 = id - 32768;
        const int s = i2 & 31, c1 = (i2 >> 5) & 63, c0 = i2 >> 11;
        float acc = 0.f;
        #pragma unroll
        for (int r = 0; r < 32; ++r)
            acc = fmaf(core0[c0 * 32 + r], mid[(r * 64 + c1) * 32 + s], acc);
        T01[(c0 * 64 + c1) * 32 + s] = __float2half(acc * 256.0f);
    } else {
        const int i3 = id - 163840;
        const int c7 = i3 & 63, c6 = (i3 >> 6) & 63, r = i3 >> 12;
        const float* m5 = mid + 5 * 65536;
        float acc = 0.f;
        #pragma unroll
        for (int s = 0; s < 32; ++s)
            acc = fmaf(m5[(r * 64 + c6) * 32 + s], lastc[s * 64 + c7], acc);
        TL[(c6 * 64 + c7) * 32 + r] = acc * 256.0f;
    }
}

// ---------------- K2: main --------------------------------------------------
__global__ __launch_bounds__(256) void tt_main_t(
    const int* __restrict__ idx, const __half* __restrict__ T01,
    const half8* __restrict__ PKB, const float* __restrict__ TL,
    float* __restrict__ out)
{
    __shared__ __align__(16) __half vbuf[S_BLK * VSTRIDE_H];  // 20 KB
    __shared__ unsigned short ord[4][S_BLK];                  // 2 KB
    __shared__ unsigned char  cols[S_BLK][8];                 // 2 KB
    __shared__ unsigned int   bases[4][65];                   // 1040 B
    __shared__ unsigned int   hist[4][64];                    // 1 KB

    const int tid  = threadIdx.x;          // == sample id within block
    const int lane = tid & 63;
    const int wv   = tid >> 6;             // 0..3
    const int li   = lane & 15;
    const int quad = lane >> 4;
    const int b0   = blockIdx.x * S_BLK;

    // Phase 0: indices -> cols (coalesced); zero hist
    #pragma unroll
    for (int k = 0; k < S_BLK * 8; k += THREADS) {
        const int lin = k + tid;
        int v = idx[b0 * 8 + lin];
        v = min(max(v, 0), NDIM - 1);
        cols[lin >> 3][lin & 7] = (unsigned char)v;
    }
    hist[tid >> 6][tid & 63] = 0;
    __syncthreads();

    // Phase 1: fused 4-key counting sort (thread == sample, ranks in regs)
    unsigned int key[4], rank[4];
    #pragma unroll
    for (int tt = 0; tt < 4; ++tt) {
        key[tt]  = cols[tid][2 + tt];
        rank[tt] = atomicAdd(&hist[tt][key[tt]], 1u);
    }
    __syncthreads();
    {   // wave wv scans hist[wv] (64 bins, one lane each)
        const unsigned int v = hist[wv][lane];
        unsigned int inc = v;
        #pragma unroll
        for (int d = 1; d < 64; d <<= 1) {
            const unsigned int n = __shfl_up(inc, d);
            if (lane >= d) inc += n;
        }
        bases[wv][lane] = inc - v;
        if (lane == 63) bases[wv][64] = inc;   // == S_BLK
    }
    __syncthreads();
    #pragma unroll
    for (int tt = 0; tt < 4; ++tt)
        ord[tt][bases[tt][key[tt]] + rank[tt]] = (unsigned short)tid;
    __syncthreads();

    // Phase 2: init v from T01 (8-lane groups; x256 true value)
    {
        const int g = tid & 7, gid = tid >> 3;
        #pragma unroll
        for (int it = 0; it < S_BLK / 32; ++it) {
            const int s = it * 32 + gid;
            const int c0 = cols[s][0], c1 = cols[s][1];
            const uint2 q = *reinterpret_cast<const uint2*>(
                T01 + (c0 * 64 + c1) * 32 + 4 * g);
            unsigned int* vp = reinterpret_cast<unsigned int*>(vbuf) + s * (VSTRIDE_H / 2);
            vp[2 * g]     = q.x;
            vp[2 * g + 1] = q.y;
        }
    }
    __syncthreads();

    // Phase 3: 4 middle stages; wave wv owns columns [16wv, 16wv+16)
    for (int tt = 0; tt < 4; ++tt) {
        const int cbase = wv * 16;
        half8 A0 = PKB[((tt * 64 + cbase) * 2 + 0) * 64 + lane];
        half8 A1 = PKB[((tt * 64 + cbase) * 2 + 1) * 64 + lane];
        for (int ci = 0; ci < 16; ++ci) {
            const int c = cbase + ci;
            half8 nA0 = A0, nA1 = A1;
            if (ci < 15) {   // prefetch next column's fragments
                nA0 = PKB[((tt * 64 + c + 1) * 2 + 0) * 64 + lane];
                nA1 = PKB[((tt * 64 + c + 1) * 2 + 1) * 64 + lane];
            }
            const int start = (int)bases[tt][c];
            const int end   = (int)bases[tt][c + 1];
            for (int p = start; p < end; p += 16) {
                const int pos = min(p + li, end - 1);
                const int sm  = (int)ord[tt][pos];     // per-li; quads broadcast
                // B: V rows, lane (q,li) holds v[sm(li)][q*8..q*8+7]
                const half8 Bv = *reinterpret_cast<const half8*>(
                    reinterpret_cast<const char*>(vbuf) + sm * 80 + quad * 16);
                f32x4 d0 = {0.f, 0.f, 0.f, 0.f}, d1 = {0.f, 0.f, 0.f, 0.f};
                d0 = __builtin_amdgcn_mfma_f32_16x16x32_f16(A0, Bv, d0, 0, 0, 0);
                d1 = __builtin_amdgcn_mfma_f32_16x16x32_f16(A1, Bv, d1, 0, 0, 0);
                // D: lane (q,li) = new_v[sample li][s_out = f*16 + q*4 + r]
                half4 w0, w1;
                #pragma unroll
                for (int r = 0; r < 4; ++r) {
                    w0[r] = (_Float16)d0[r];
                    w1[r] = (_Float16)d1[r];
                }
                char* base = reinterpret_cast<char*>(vbuf) + sm * 80 + quad * 8;
                *reinterpret_cast<half4*>(base)      = w0;   // s_out quad*4..+3
                *reinterpret_cast<half4*>(base + 32) = w1;   // s_out 16+quad*4..+3
            }
            A0 = nA0; A1 = nA1;
        }
        __syncthreads();
    }

    // Phase 4: final contraction vs TL (x256), 8-lane reduce, undo 2^32
    {
        const int g = tid & 7, gid = tid >> 3;
        #pragma unroll
        for (int it = 0; it < S_BLK / 32; ++it) {
            const int s = it * 32 + gid;
            const int c6 = cols[s][6], c7 = cols[s][7];
            const unsigned int* vp =
                reinterpret_cast<const unsigned int*>(vbuf) + s * (VSTRIDE_H / 2);
            const __half2 v01 = *reinterpret_cast<const __half2*>(&vp[2 * g]);
            const __half2 v23 = *reinterpret_cast<const __half2*>(&vp[2 * g + 1]);
            const float4 L = *reinterpret_cast<const float4*>(
                TL + (c6 * 64 + c7) * 32 + 4 * g);
            float o = 0.f;
            o = fmaf(__low2float(v01),  L.x, o);
            o = fmaf(__high2float(v01), L.y, o);
            o = fmaf(__low2float(v23),  L.z, o);
            o = fmaf(__high2float(v23), L.w, o);
            o += __shfl_xor(o, 1);
            o += __shfl_xor(o, 2);
            o += __shfl_xor(o, 4);
            if (g == 0) out[b0 + s] = o * 2.3283064365386963e-10f;   // 2^-32
        }
    }
}

// ---------------- host ------------------------------------------------------
// ws: PKB 524288 B | TL 524288 B | T01 262144 B  (1310720 B total)
#define PKB_OFF 0u
#define TL_OFF  524288u
#define T01_OFF 1048576u

extern "C" void kernel_launch(void* const* d_in, const int* in_sizes, int n_in,
                              void* d_out, int out_size, void* d_ws, size_t ws_size,
                              hipStream_t stream) {
    const int*   idx   = (const int*)d_in[0];    // (B, 8) int32
    const float* core0 = (const float*)d_in[1];  // (1, 64, 32)
    const float* mid   = (const float*)d_in[2];  // (6, 32, 64, 32)
    const float* lastc = (const float*)d_in[3];  // (32, 64, 1)
    float* out = (float*)d_out;

    half8*  PKB = (half8*)((char*)d_ws + PKB_OFF);
    float*  TL  = (float*)((char*)d_ws + TL_OFF);
    __half* T01 = (__half*)((char*)d_ws + T01_OFF);

    hipLaunchKernelGGL(build_tables, dim3(294912 / 256), dim3(256), 0, stream,
                       core0, mid, lastc, PKB, T01, TL);
    hipLaunchKernelGGL(tt_main_t, dim3(B_TOTAL / S_BLK), dim3(THREADS), 0, stream,
                       idx, T01, PKB, TL, out);
}